// Round 10
// baseline (5581.924 us; speedup 1.0000x reference)
//
#include <hip/hip_runtime.h>

typedef __bf16 bf16x8 __attribute__((ext_vector_type(8)));
typedef float f32x4 __attribute__((ext_vector_type(4)));

#define T_STEPS 1024
#define H_SZ    1024
#define F_IN    256
#define NGR     8    // groups (chains); pair (2p, 2p+1) shares a WG set
#define NB      8    // batches per group
#define WPG     64   // workgroups per pair-set (and per chain)
#define SPIN_MAX (1 << 15)   // bounded: bail -> sticky skip, graceful fail

__device__ __forceinline__ unsigned short f2bf(float f) {
    union { float f; unsigned u; } v; v.f = f;
    unsigned r = v.u + 0x7fffu + ((v.u >> 16) & 1u);
    return (unsigned short)(r >> 16);
}

__device__ __forceinline__ float fsigmoid(float x) {
    return 1.0f / (1.0f + __expf(-x));
}
__device__ __forceinline__ float ftanh(float x) {
    return 1.0f - 2.0f / (__expf(2.0f * x) + 1.0f);
}

// Conflict-free LDS index (verified R1/R4). bank = (4h+b)%32, bijective.
__device__ __forceinline__ int redidx(int h, int b) {
    return ((4 * h + b) & 31) + 32 * ((h >> 3) * 4 + (b >> 2));
}

// Issue 8 coherent 16B loads, NO waitcnt (caller waits; rule #18 applies).
__device__ __forceinline__ void issue_h8(const unsigned short* p,
    bf16x8& h0, bf16x8& h1, bf16x8& h2, bf16x8& h3,
    bf16x8& h4, bf16x8& h5, bf16x8& h6, bf16x8& h7)
{
    asm volatile(
        "global_load_dwordx4 %0, %8, off sc0 sc1\n\t"
        "global_load_dwordx4 %1, %8, off offset:64 sc0 sc1\n\t"
        "global_load_dwordx4 %2, %8, off offset:128 sc0 sc1\n\t"
        "global_load_dwordx4 %3, %8, off offset:192 sc0 sc1\n\t"
        "global_load_dwordx4 %4, %8, off offset:256 sc0 sc1\n\t"
        "global_load_dwordx4 %5, %8, off offset:320 sc0 sc1\n\t"
        "global_load_dwordx4 %6, %8, off offset:384 sc0 sc1\n\t"
        "global_load_dwordx4 %7, %8, off offset:448 sc0 sc1"
        : "=&v"(h0), "=&v"(h1), "=&v"(h2), "=&v"(h3),
          "=&v"(h4), "=&v"(h5), "=&v"(h6), "=&v"(h7)
        : "v"(p) : "memory");
}

// ---------------------------------------------------------------------------
// Gaussian blur (sigma=1, radius=4, edge padding), both axes fused.
// ---------------------------------------------------------------------------
__global__ __launch_bounds__(256) void blur_kernel(
    const float* __restrict__ x, unsigned short* __restrict__ xb)
{
    __shared__ float tb[64][256];
    const float kk[9] = {
        0.000133831f, 0.0044318617f, 0.0539911273f, 0.2419714457f,
        0.3989434694f,
        0.2419714457f, 0.0539911273f, 0.0044318617f, 0.000133831f };

    const int b     = blockIdx.x >> 4;
    const int chunk = blockIdx.x & 15;
    const int t0    = chunk * 64;
    const int f     = threadIdx.x;
    const float* xbase = x + (size_t)b * T_STEPS * F_IN;

    for (int r = 0; r < 64; r++) {
        int t = t0 + r;
        float acc = 0.0f;
        #pragma unroll
        for (int d = 0; d < 9; d++) {
            int ts = t + d - 4;
            ts = min(max(ts, 0), T_STEPS - 1);
            acc += kk[d] * xbase[ts * F_IN + f];
        }
        tb[r][f] = acc;
    }
    __syncthreads();
    for (int r = 0; r < 64; r++) {
        float acc = 0.0f;
        #pragma unroll
        for (int d = 0; d < 9; d++) {
            int fs = f + d - 4;
            fs = min(max(fs, 0), F_IN - 1);
            acc += kk[d] * tb[r][fs];
        }
        xb[((size_t)b * T_STEPS + t0 + r) * F_IN + f] = f2bf(acc);
    }
}

// ---------------------------------------------------------------------------
// Persistent dual-chain LSTM. 256 WGs x 256 threads, cooperative (the ONLY
// proven-launchable envelope: grid 256, VGPR ~150, LDS 16KB).
//
// 8 groups x 8 batches. WG set pid=wg>>6 (64 WGs) serves chain A=2*pid and
// chain B=2*pid+1 with the SAME weight registers. Per iteration: phase A
// then phase B, each an R4-protocol step (sc0 sc1 exchange, 4-line x
// 16-RMW barrier, tid<4 poll). Chain X's barrier settle elapses during
// chain Y's phase; h-load RT of Y merges into X's store drain.
//
// Hardening vs R9: SPIN_MAX = 2^15 with a STICKY bail (first bail disables
// all further polls in that thread) -> worst-case overrun ~100 ms, a
// graceful visible numeric fail, never a container-watchdog kill.
//
// Safety: per-chain protocol identical to R4 (proven). Poll X(t-1)
// precedes any X(t) store; arrive X(t) follows X-store drain; counters
// monotonic, fresh lines per step -> no circular wait. sched_barrier(0)
// after each guard-waitcnt (rule #18).
// ---------------------------------------------------------------------------
__global__ __launch_bounds__(256, 1) void lstm_persist(
    const unsigned short* __restrict__ xb,   // [64][1024][256] bf16
    const float* __restrict__ Whh,           // [4096][1024]
    const float* __restrict__ Wih,           // [4096][256]
    const float* __restrict__ bih,           // [4096]
    const float* __restrict__ bhh,           // [4096]
    unsigned short* __restrict__ hbuf,       // [2][64][1024] bf16
    unsigned int* __restrict__ arrive)       // [8][1024][64] dwords
{
    const int wg   = blockIdx.x;
    const int pid  = wg >> 6;         // pair-set 0..3
    const int w    = wg & 63;         // slot: hid rows w*16..w*16+16
    const int tid  = threadIdx.x;
    const int q    = tid >> 6;        // wave id = K-quarter
    const int lane = tid & 63;
    const int lrow = lane & 15;       // A: m-row / B: n-col
    const int lq   = lane >> 4;       // quad
    const int bl   = lrow & 7;        // batch within group (dup for lrow>=8)
    const int gA   = pid * 2;
    const int gB   = pid * 2 + 1;

    __shared__ float red[4][4][256];  // conflict-free reduce (16 KiB)

    // ---- weight fragments, shared by both chains ----
    bf16x8 wa[8][4];
    bf16x8 wx[2][4];
    const int row_lo = w * 16 + lrow;
    #pragma unroll
    for (int kt = 0; kt < 8; kt++) {
        const int kofs = q * 256 + kt * 32 + lq * 8;
        #pragma unroll
        for (int g = 0; g < 4; g++) {
            const float* src = Whh + (size_t)(g * H_SZ + row_lo) * H_SZ + kofs;
            union { bf16x8 v; unsigned short s[8]; } u;
            #pragma unroll
            for (int j = 0; j < 8; j++) u.s[j] = f2bf(src[j]);
            wa[kt][g] = u.v;
        }
    }
    #pragma unroll
    for (int kt = 0; kt < 2; kt++) {
        const int kofs = q * 64 + kt * 32 + lq * 8;
        #pragma unroll
        for (int g = 0; g < 4; g++) {
            const float* src = Wih + (size_t)(g * H_SZ + row_lo) * F_IN + kofs;
            union { bf16x8 v; unsigned short s[8]; } u;
            #pragma unroll
            for (int j = 0; j < 8; j++) u.s[j] = f2bf(src[j]);
            wx[kt][g] = u.v;
        }
    }

    // ---- update-phase mapping (tid<128): 16 hid x 8 batch ----
    const int uhid = tid & 15;
    const int ub   = (tid >> 4) & 7;
    float bias[4];
    #pragma unroll
    for (int g = 0; g < 4; g++) {
        int r = g * H_SZ + w * 16 + uhid;
        bias[g] = bih[r] + bhh[r];
    }
    float cA = 0.0f, cB = 0.0f;

    // ---- bases ----
    const int bA = pid * 16 + bl;          // chain A batch (this lane)
    const unsigned short* xbaseA =
        xb + ((size_t)bA * T_STEPS) * F_IN + q * 64 + lq * 8;
    const unsigned short* xbaseB = xbaseA + (size_t)8 * T_STEPS * F_IN;
    unsigned short* hdstA =
        hbuf + (size_t)(pid * 16 + ub) * H_SZ + w * 16 + uhid;
    unsigned short* hdstB = hdstA + (size_t)8 * H_SZ;
    const unsigned short* hsrcA =
        hbuf + (size_t)bA * H_SZ + q * 256 + lq * 8;
    const unsigned short* hsrcB = hsrcA + (size_t)8 * H_SZ;

    int wofs[4];
    #pragma unroll
    for (int e = 0; e < 4; e++) wofs[e] = redidx(lq * 4 + e, bl);
    const int rofs = redidx(uhid, ub);

    bf16x8 hf0, hf1, hf2, hf3, hf4, hf5, hf6, hf7;
    int bail = 0;   // sticky: once any poll bails, stop polling entirely

    // ---- prologue: hA(-1) = h0 = 0 lives in parity slot 1 (memset) ----
    issue_h8(hsrcA + (size_t)64 * H_SZ, hf0, hf1, hf2, hf3, hf4, hf5, hf6, hf7);

    for (int t = 0; t < T_STEPS; t++) {
        const size_t par  = (size_t)(t & 1) * 64 * H_SZ;
        const size_t parp = (size_t)((t & 1) ^ 1) * 64 * H_SZ;

        // x fragments for both chains (latency merged into the wait below)
        const unsigned short* xrA = xbaseA + (size_t)t * F_IN;
        const unsigned short* xrB = xbaseB + (size_t)t * F_IN;
        bf16x8 xA0 = *reinterpret_cast<const bf16x8*>(xrA);
        bf16x8 xA1 = *reinterpret_cast<const bf16x8*>(xrA + 32);
        bf16x8 xB0 = *reinterpret_cast<const bf16x8*>(xrB);
        bf16x8 xB1 = *reinterpret_cast<const bf16x8*>(xrB + 32);

        // ================= phase A: chain gA, step t =================
        asm volatile("s_waitcnt vmcnt(0)" ::: "memory");  // hA + x ready
        __builtin_amdgcn_sched_barrier(0);

        f32x4 acc[4];
        #pragma unroll
        for (int g = 0; g < 4; g++) acc[g] = (f32x4){0.f, 0.f, 0.f, 0.f};
        {
            bf16x8 hfa[8] = { hf0, hf1, hf2, hf3, hf4, hf5, hf6, hf7 };
            #pragma unroll
            for (int kt = 0; kt < 8; kt++)
                #pragma unroll
                for (int g = 0; g < 4; g++)
                    acc[g] = __builtin_amdgcn_mfma_f32_16x16x32_bf16(
                        wa[kt][g], hfa[kt], acc[g], 0, 0, 0);
        }
        #pragma unroll
        for (int g = 0; g < 4; g++) {
            acc[g] = __builtin_amdgcn_mfma_f32_16x16x32_bf16(wx[0][g], xA0, acc[g], 0, 0, 0);
            acc[g] = __builtin_amdgcn_mfma_f32_16x16x32_bf16(wx[1][g], xA1, acc[g], 0, 0, 0);
        }
        if (lrow < 8) {
            #pragma unroll
            for (int g = 0; g < 4; g++)
                #pragma unroll
                for (int e = 0; e < 4; e++)
                    red[q][g][wofs[e]] = acc[g][e];
        }
        __syncthreads();                                   // S1

        unsigned short hbA = 0;
        if (tid < 128) {
            float gv[4];
            #pragma unroll
            for (int g = 0; g < 4; g++) {
                float s = bias[g];
                #pragma unroll
                for (int qq = 0; qq < 4; qq++) s += red[qq][g][rofs];
                gv[g] = s;
            }
            float ig = fsigmoid(gv[0]), fg = fsigmoid(gv[1]);
            float gz = ftanh(gv[2]),    og = fsigmoid(gv[3]);
            cA = fg * cA + ig * gz;
            hbA = f2bf(og * ftanh(cA));
        }

        // poll B(t-1): settled during our phase-A work + prior slack
        if (t > 0 && tid < 4 && !bail) {
            const unsigned int* p =
                arrive + (((size_t)gB * T_STEPS + (t - 1)) << 6) + tid * 16;
            unsigned v; int sp = 0;
            for (;;) {
                asm volatile("global_load_dword %0, %1, off sc0 sc1\n\t"
                             "s_waitcnt vmcnt(0)"
                             : "=v"(v) : "v"(p) : "memory");
                if (v >= 16u) break;
                if (++sp > SPIN_MAX) { bail = 1; break; }
            }
        }
        __syncthreads();                                   // S2

        // issue hB(t-1) loads; their RT merges into the store-A drain
        issue_h8(hsrcB + parp, hf0, hf1, hf2, hf3, hf4, hf5, hf6, hf7);

        if (tid < 128)
            asm volatile("global_store_short %0, %1, off sc0 sc1"
                         :: "v"(hdstA + par), "v"(hbA) : "memory");
        asm volatile("s_waitcnt vmcnt(0)" ::: "memory");   // store A + hB done
        __builtin_amdgcn_sched_barrier(0);
        __syncthreads();                                   // S3
        if (tid == 0)
            asm volatile("global_atomic_add %0, %1, off"
                         :: "v"(arrive + (((size_t)gA * T_STEPS + t) << 6)
                                 + (w & 3) * 16), "v"(1u) : "memory");

        // ================= phase B: chain gB, step t =================
        #pragma unroll
        for (int g = 0; g < 4; g++) acc[g] = (f32x4){0.f, 0.f, 0.f, 0.f};
        {
            bf16x8 hfb[8] = { hf0, hf1, hf2, hf3, hf4, hf5, hf6, hf7 };
            #pragma unroll
            for (int kt = 0; kt < 8; kt++)
                #pragma unroll
                for (int g = 0; g < 4; g++)
                    acc[g] = __builtin_amdgcn_mfma_f32_16x16x32_bf16(
                        wa[kt][g], hfb[kt], acc[g], 0, 0, 0);
        }
        #pragma unroll
        for (int g = 0; g < 4; g++) {
            acc[g] = __builtin_amdgcn_mfma_f32_16x16x32_bf16(wx[0][g], xB0, acc[g], 0, 0, 0);
            acc[g] = __builtin_amdgcn_mfma_f32_16x16x32_bf16(wx[1][g], xB1, acc[g], 0, 0, 0);
        }
        if (lrow < 8) {
            #pragma unroll
            for (int g = 0; g < 4; g++)
                #pragma unroll
                for (int e = 0; e < 4; e++)
                    red[q][g][wofs[e]] = acc[g][e];
        }
        __syncthreads();                                   // S4

        unsigned short hbB = 0;
        if (tid < 128) {
            float gv[4];
            #pragma unroll
            for (int g = 0; g < 4; g++) {
                float s = bias[g];
                #pragma unroll
                for (int qq = 0; qq < 4; qq++) s += red[qq][g][rofs];
                gv[g] = s;
            }
            float ig = fsigmoid(gv[0]), fg = fsigmoid(gv[1]);
            float gz = ftanh(gv[2]),    og = fsigmoid(gv[3]);
            cB = fg * cB + ig * gz;
            hbB = f2bf(og * ftanh(cB));
        }

        // poll A(t): arrivals posted at S3 this iteration; settled during
        // our phase-B work
        if (tid < 4 && !bail) {
            const unsigned int* p =
                arrive + (((size_t)gA * T_STEPS + t) << 6) + tid * 16;
            unsigned v; int sp = 0;
            for (;;) {
                asm volatile("global_load_dword %0, %1, off sc0 sc1\n\t"
                             "s_waitcnt vmcnt(0)"
                             : "=v"(v) : "v"(p) : "memory");
                if (v >= 16u) break;
                if (++sp > SPIN_MAX) { bail = 1; break; }
            }
        }
        __syncthreads();                                   // S5

        // issue hA(t) loads for the next iteration; RT merges into store-B
        // drain. (Last iteration: harmless dead loads.)
        issue_h8(hsrcA + par, hf0, hf1, hf2, hf3, hf4, hf5, hf6, hf7);

        if (tid < 128)
            asm volatile("global_store_short %0, %1, off sc0 sc1"
                         :: "v"(hdstB + par), "v"(hbB) : "memory");
        asm volatile("s_waitcnt vmcnt(0)" ::: "memory");   // store B + hA done
        __builtin_amdgcn_sched_barrier(0);
        __syncthreads();                                   // S6
        if (tid == 0)
            asm volatile("global_atomic_add %0, %1, off"
                         :: "v"(arrive + (((size_t)gB * T_STEPS + t) << 6)
                                 + (w & 3) * 16), "v"(1u) : "memory");
    }
}

// ---------------------------------------------------------------------------
// out[b][o] = h_last[b] . W_fc[o] + b_fc[o].  64 blocks x 256 threads.
// ---------------------------------------------------------------------------
__global__ __launch_bounds__(256) void final_fc(
    const unsigned short* __restrict__ hbuf,  // parity-1 holds h_last
    const float* __restrict__ Wfc, const float* __restrict__ bfc,
    float* __restrict__ out)
{
    __shared__ float hs[H_SZ];
    const int b = blockIdx.x;
    const unsigned short* hrow = hbuf + (size_t)64 * H_SZ + (size_t)b * H_SZ;
    for (int k = threadIdx.x; k < H_SZ; k += 256) {
        union { unsigned u; float f; } cv;
        cv.u = ((unsigned)hrow[k]) << 16;
        hs[k] = cv.f;
    }
    __syncthreads();
    const int o = threadIdx.x;
    const float4* wr = reinterpret_cast<const float4*>(Wfc + (size_t)o * H_SZ);
    float acc = bfc[o];
    for (int k4 = 0; k4 < H_SZ / 4; k4++) {
        float4 wv = wr[k4];
        acc += hs[k4 * 4 + 0] * wv.x + hs[k4 * 4 + 1] * wv.y
             + hs[k4 * 4 + 2] * wv.z + hs[k4 * 4 + 3] * wv.w;
    }
    out[(size_t)b * 256 + o] = acc;
}

// ---------------------------------------------------------------------------
extern "C" void kernel_launch(void* const* d_in, const int* in_sizes, int n_in,
                              void* d_out, int out_size, void* d_ws,
                              size_t ws_size, hipStream_t stream)
{
    (void)in_sizes; (void)n_in; (void)out_size; (void)ws_size;
    const float* x   = (const float*)d_in[0];
    const float* Wih = (const float*)d_in[1];
    const float* Whh = (const float*)d_in[2];
    const float* bih = (const float*)d_in[3];
    const float* bhh = (const float*)d_in[4];
    const float* Wfc = (const float*)d_in[5];
    const float* bfc = (const float*)d_in[6];
    float* out = (float*)d_out;

    char* ws = (char*)d_ws;
    unsigned short* xblur = (unsigned short*)ws;                     // 33,554,432 B
    unsigned short* hbuf  = (unsigned short*)(ws + 33554432);        // 262,144 B
    unsigned int*   arrv  = (unsigned int*)(ws + 33554432 + 262144); // 2,097,152 B

    // zero h0 (both parity slots) and barrier sub-counters
    hipMemsetAsync(hbuf, 0, 262144 + 2097152, stream);

    blur_kernel<<<dim3(1024), dim3(256), 0, stream>>>(x, xblur);

    void* kargs[] = { (void*)&xblur, (void*)&Whh, (void*)&Wih,
                      (void*)&bih, (void*)&bhh, (void*)&hbuf, (void*)&arrv };
    hipLaunchCooperativeKernel((void*)lstm_persist, dim3(256), dim3(256),
                               kargs, 0, stream);

    final_fc<<<dim3(64), dim3(256), 0, stream>>>(hbuf, Wfc, bfc, out);
}